// Round 25
// baseline (541.495 us; speedup 1.0000x reference)
//
#include <hip/hip_runtime.h>
#include <math.h>
#include <limits.h>

#define NPTS    50000
#define NCHUNK  16
#define CHUNK   3328             // float4s per chunk (xy plane 1664 + zs plane 1664)
#define CBUN    1664             // bundles per chunk (2 pts/bundle)
#define NGROUP  13
#define NPAD    (NCHUNK * CHUNK) // 53248 float4s total packed
#define NBUN    (NCHUNK * CBUN)  // 26624 bundles
#define NQ      4000
#define KNN     4
#define QG      8                // queries per wave
#define NBLK    4000             // 500 qg x 8 chunk-pairs; 4 waves = 2 chunks x 2 halves
#define CAP     14               // per-(query,chunk) pool (u16 index-only)
#define BIGF    3.0e38f

// workspace layout (bytes)
#define PK_OFF  0
#define CNT_OFF (NPAD * 16)                          // 851968
#define IL_OFF  (CNT_OFF + NQ * NCHUNK * 4)          // 979968 (cnt u16, padded region ok)
#define WS_NEED (IL_OFF + NQ * NCHUNK * CAP * 2)     // 2771968 (< 2887296 proven)

typedef float v2f __attribute__((ext_vector_type(2)));

// lex (dist, idx) insert into sorted ascending 4-list
__device__ __forceinline__ void lex_insert(float (&bd)[KNN], int (&bi)[KNN],
                                           float dist, int idx) {
    if (dist < bd[KNN - 1] || (dist == bd[KNN - 1] && idx < bi[KNN - 1])) {
        bd[KNN - 1] = dist; bi[KNN - 1] = idx;
#pragma unroll
        for (int k = KNN - 1; k > 0; --k) {
            bool sw = (bd[k] < bd[k - 1]) || (bd[k] == bd[k - 1] && bi[k] < bi[k - 1]);
            if (sw) {
                float td = bd[k]; bd[k] = bd[k - 1]; bd[k - 1] = td;
                int   ti = bi[k]; bi[k] = bi[k - 1]; bi[k - 1] = ti;
            }
        }
    }
}

// butterfly merge of per-lane sorted 4-lists -> wave-global lex top-4 (all lanes)
__device__ __forceinline__ void wave_merge4(float (&bd)[KNN], int (&bi)[KNN]) {
    for (int m = 1; m < 64; m <<= 1) {
        float od[KNN]; int oi[KNN];
#pragma unroll
        for (int j = 0; j < KNN; ++j) {
            od[j] = __shfl_xor(bd[j], m, 64);
            oi[j] = __shfl_xor(bi[j], m, 64);
        }
        float md[KNN]; int mi[KNN]; int a = 0, b = 0;
#pragma unroll
        for (int j = 0; j < KNN; ++j) {
            const bool takeA = (bd[a] < od[b]) || (bd[a] == od[b] && bi[a] <= oi[b]);
            if (takeA) { md[j] = bd[a]; mi[j] = bi[a]; ++a; }
            else       { md[j] = od[b]; mi[j] = oi[b]; ++b; }
        }
#pragma unroll
        for (int j = 0; j < KNN; ++j) { bd[j] = md[j]; bi[j] = mi[j]; }
    }
}

// ---------------- pack: chunk-major SoA planes: xy[1664] then zs[1664] ------
__global__ __launch_bounds__(256) void pack_kernel(const float* __restrict__ pts,
                                                   float4* __restrict__ packed) {
    int t = blockIdx.x * 256 + threadIdx.x;   // grid = NBUN/256 = 104
    int p0 = 2 * t, p1 = 2 * t + 1;
    float x0 = 0.f, y0 = 0.f, z0 = 0.f, s0 = BIGF;
    float x1 = 0.f, y1 = 0.f, z1 = 0.f, s1 = BIGF;
    if (p0 < NPTS) {
        x0 = pts[3*p0]; y0 = pts[3*p0+1]; z0 = pts[3*p0+2];
        s0 = __fadd_rn(__fadd_rn(__fmul_rn(x0,x0), __fmul_rn(y0,y0)), __fmul_rn(z0,z0));
    }
    if (p1 < NPTS) {
        x1 = pts[3*p1]; y1 = pts[3*p1+1]; z1 = pts[3*p1+2];
        s1 = __fadd_rn(__fadd_rn(__fmul_rn(x1,x1), __fmul_rn(y1,y1)), __fmul_rn(z1,z1));
    }
    const int c = t / CBUN, i = t - c * CBUN;
    packed[c * CHUNK + i]        = make_float4(x0, x1, y0, y1);   // xy plane
    packed[c * CHUNK + CBUN + i] = make_float4(z0, z1, s0, s1);   // zs plane
}

// packed filter distance for a bundle: d2' = fma chain + s
__device__ __forceinline__ v2f d2pk(float mx, float my, float mz, float qs,
                                    float4 XY, float4 ZS) {
    v2f x = {XY.x, XY.y}, y = {XY.z, XY.w}, z = {ZS.x, ZS.y}, s = {ZS.z, ZS.w};
    v2f t = __builtin_elementwise_fma((v2f){mx, mx}, x, (v2f){qs, qs});
    t = __builtin_elementwise_fma((v2f){my, my}, y, t);
    t = __builtin_elementwise_fma((v2f){mz, mz}, z, t);
    return t + s;
}

// ---------------- main: GLOBAL reads + LDS pools, 2 waves per chunk ---------
// block b: qg = b>>3, chunk-pair cp = b&7. Wave widx: chunk = 2*cp+(widx>>1),
// half = widx&1 scans groups g = half, half+2, ... Two halves share LDS pools.
__global__ __launch_bounds__(256) void knn_main(const float4* __restrict__ pk4,
                                                const float* __restrict__ queries,
                                                unsigned short* __restrict__ cnt,
                                                unsigned short* __restrict__ il) {
    __shared__ int scnt[16];                  // 2 chunks x 8 queries
    __shared__ unsigned short sil[16][CAP];

    const int lane  = threadIdx.x & 63;
    const int widx  = threadIdx.x >> 6;
    const int qg    = blockIdx.x >> 3;                // [0, 500), uniform in block
    const int cp    = blockIdx.x & 7;
    const int cloc  = widx >> 1;                      // chunk-within-block 0/1
    const int chunk = 2 * cp + cloc;
    const int half  = widx & 1;
    const int qbase = qg * QG;

    if (threadIdx.x < 16) scnt[threadIdx.x] = 0;

    float mx[QG], my[QG], mz[QG], qs[QG];
#pragma unroll
    for (int j = 0; j < QG; ++j) {
        float a = queries[(qbase + j) * 3 + 0];
        float b = queries[(qbase + j) * 3 + 1];
        float c = queries[(qbase + j) * 3 + 2];
        mx[j] = __fmul_rn(-2.f, a);
        my[j] = __fmul_rn(-2.f, b);
        mz[j] = __fmul_rn(-2.f, c);
        qs[j] = __fadd_rn(__fadd_rn(__fmul_rn(a, a), __fmul_rn(b, b)),
                          __fmul_rn(c, c));
    }
    __syncthreads();

    const float4* xy = pk4 + chunk * CHUNK;   // xy plane of this wave's chunk
    const float4* zs = xy + CBUN;             // zs plane

    // ---- pass A: per-lane packed min of d2' per query (my half's groups) ---
    v2f mn[QG];
#pragma unroll
    for (int j = 0; j < QG; ++j) mn[j] = (v2f){BIGF, BIGF};

#pragma unroll 1
    for (int g = half; g < NGROUP; g += 2) {
        const int bA = g * 128 + lane;
        float4 A1 = xy[bA],      A2 = zs[bA];
        float4 B1 = xy[bA + 64], B2 = zs[bA + 64];
#pragma unroll
        for (int j = 0; j < QG; ++j) {
            v2f ta = d2pk(mx[j], my[j], mz[j], qs[j], A1, A2);
            v2f tb = d2pk(mx[j], my[j], mz[j], qs[j], B1, B2);
            mn[j] = __builtin_elementwise_min(mn[j],
                        __builtin_elementwise_min(ta, tb));
        }
    }

    // ---- tau2 (per half): 4th-distinct-smallest of 64 lane mins + margin ---
    // valid: any true chunk-top-4 point in this half has d2 <= chunk-4th <=
    // this half's 4th-distinct lane-min <= tau2 -> captured.
    float tau2[QG];
#pragma unroll
    for (int j = 0; j < QG; ++j) {
        float v = fminf(mn[j].x, mn[j].y), tau = v;
#pragma unroll
        for (int r = 0; r < 4; ++r) {
            float t = v;
#pragma unroll
            for (int s = 1; s < 64; s <<= 1) t = fminf(t, __shfl_xor(t, s, 64));
            tau = t;
            v = (v == t) ? BIGF : v;
        }
        tau2[j] = fmaf(tau, 1.00001f, 1e-4f);   // covers packed-vs-exact + sqrt ties
    }

    // ---- pass B: rescan my half's groups, pushes into SHARED LDS pools ----
#pragma unroll 1
    for (int g = half; g < NGROUP; g += 2) {
        const int bA = g * 128 + lane;
        float4 A1 = xy[bA],      A2 = zs[bA];
        float4 B1 = xy[bA + 64], B2 = zs[bA + 64];
        const int pb = 2 * (chunk * CBUN + bA);        // global point idx of A.x
#pragma unroll
        for (int j = 0; j < QG; ++j) {
            v2f ta = d2pk(mx[j], my[j], mz[j], qs[j], A1, A2);
            v2f tb = d2pk(mx[j], my[j], mz[j], qs[j], B1, B2);
            v2f m2 = __builtin_elementwise_min(ta, tb);
            float m1 = fminf(m2.x, m2.y);
            if (m1 <= tau2[j]) {
                const int lp = cloc * QG + j;          // shared pool [0,16)
                if (ta.x <= tau2[j]) { int pos = atomicAdd(&scnt[lp], 1); if (pos < CAP) sil[lp][pos] = (unsigned short)pb; }
                if (ta.y <= tau2[j]) { int pos = atomicAdd(&scnt[lp], 1); if (pos < CAP) sil[lp][pos] = (unsigned short)(pb + 1); }
                if (tb.x <= tau2[j]) { int pos = atomicAdd(&scnt[lp], 1); if (pos < CAP) sil[lp][pos] = (unsigned short)(pb + 128); }
                if (tb.y <= tau2[j]) { int pos = atomicAdd(&scnt[lp], 1); if (pos < CAP) sil[lp][pos] = (unsigned short)(pb + 129); }
            }
        }
    }

    // ---- writeback: coalesced dump per block (no global atomics) ----
    __syncthreads();
    if (threadIdx.x < 16) {
        const int cl = threadIdx.x >> 3, j = threadIdx.x & 7;
        cnt[(qbase + j) * NCHUNK + (2 * cp + cl)] = (unsigned short)scnt[threadIdx.x];
    }
    if (threadIdx.x < 16 * CAP) {                     // 224 slots < 256 threads
        const int t = threadIdx.x / CAP, k = threadIdx.x - t * CAP;
        const int cl = t >> 3, j = t & 7;
        il[((qbase + j) * NCHUNK + (2 * cp + cl)) * CAP + k] = sil[t][k];
    }
}

// ---------------- final: one wave per query, 224 slots, EXACT arithmetic ----
__global__ __launch_bounds__(256) void knn_final(const unsigned short* __restrict__ cnt,
                                                 const unsigned short* __restrict__ il,
                                                 const float* __restrict__ points,
                                                 const float* __restrict__ queries,
                                                 float* __restrict__ out) {
    const int q    = blockIdx.x * 4 + (threadIdx.x >> 6);  // [0, 4000)
    const int lane = threadIdx.x & 63;

    const float q0 = queries[q*3+0], q1 = queries[q*3+1], q2v = queries[q*3+2];
    const float q2s = __fadd_rn(__fadd_rn(__fmul_rn(q0,q0), __fmul_rn(q1,q1)),
                                __fmul_rn(q2v,q2v));

    float bd[KNN]; int bi[KNN];
#pragma unroll
    for (int k = 0; k < KNN; ++k) { bd[k] = INFINITY; bi[k] = INT_MAX; }

    bool o = false;
#pragma unroll
    for (int t = 0; t < 4; ++t) {
        const int s = lane + t * 64;
        if (s < NCHUNK * CAP) {
            const int c = s / CAP;
            o = o || ((int)cnt[q * NCHUNK + c] > CAP);
        }
    }

    if (!__any(o)) {
#pragma unroll
        for (int t = 0; t < 4; ++t) {
            const int s = lane + t * 64;
            if (s < NCHUNK * CAP) {
                const int c = s / CAP, k = s - c * CAP;
                const int n = (int)cnt[q * NCHUNK + c];
                if (k < n) {
                    int idx = (int)il[(q * NCHUNK + c) * CAP + k];
                    float x = points[idx*3], y = points[idx*3+1], z = points[idx*3+2];
                    float p2s = __fadd_rn(__fadd_rn(__fmul_rn(x,x), __fmul_rn(y,y)), __fmul_rn(z,z));
                    float dot = __fadd_rn(__fadd_rn(__fmul_rn(q0,x), __fmul_rn(q1,y)), __fmul_rn(q2v,z));
                    float d2  = __fsub_rn(__fadd_rn(q2s, p2s), __fmul_rn(2.0f, dot));
                    lex_insert(bd, bi, __fsqrt_rn(fmaxf(d2, 0.f)), idx);
                }
            }
        }
    } else {
        // overflow repair (rare): wave-parallel brute force, exact arithmetic
        for (int p = lane; p < NPTS; p += 64) {
            float x = points[p*3], y = points[p*3+1], z = points[p*3+2];
            float p2s = __fadd_rn(__fadd_rn(__fmul_rn(x,x), __fmul_rn(y,y)), __fmul_rn(z,z));
            float dot = __fadd_rn(__fadd_rn(__fmul_rn(q0,x), __fmul_rn(q1,y)), __fmul_rn(q2v,z));
            float d2  = __fsub_rn(__fadd_rn(q2s, p2s), __fmul_rn(2.0f, dot));
            lex_insert(bd, bi, __fsqrt_rn(fmaxf(d2, 0.f)), p);
        }
    }

    wave_merge4(bd, bi);

    if (lane == 0) {
#pragma unroll
        for (int k = 0; k < KNN; ++k) {
            out[q * KNN + k]            = bd[k];
            out[NQ * KNN + q * KNN + k] = (float)bi[k];
        }
    }
}

// ---------------- fallback (round-1 kernel, passed) if ws too small ---------
__global__ __launch_bounds__(256) void knn_fallback(const float* __restrict__ points,
                                                    const float* __restrict__ queries,
                                                    float* __restrict__ out) {
    const int gtid = blockIdx.x * blockDim.x + threadIdx.x;
    const int wave = gtid >> 6;
    const int lane = threadIdx.x & 63;
    if (wave >= NQ) return;
    const float q0 = queries[wave*3+0], q1 = queries[wave*3+1], q2v = queries[wave*3+2];
    const float q2s = __fadd_rn(__fadd_rn(__fmul_rn(q0,q0), __fmul_rn(q1,q1)), __fmul_rn(q2v,q2v));
    float bd[KNN]; int bi[KNN];
#pragma unroll
    for (int j = 0; j < KNN; ++j) { bd[j] = INFINITY; bi[j] = INT_MAX; }
    for (int p = lane; p < NPTS; p += 64) {
        float x = points[p*3], y = points[p*3+1], z = points[p*3+2];
        float p2s = __fadd_rn(__fadd_rn(__fmul_rn(x,x), __fmul_rn(y,y)), __fmul_rn(z,z));
        float dot = __fadd_rn(__fadd_rn(__fmul_rn(q0,x), __fmul_rn(q1,y)), __fmul_rn(q2v,z));
        float d2 = __fsub_rn(__fadd_rn(q2s, p2s), __fmul_rn(2.0f, dot));
        lex_insert(bd, bi, __fsqrt_rn(fmaxf(d2, 0.f)), p);
    }
    wave_merge4(bd, bi);
    if (lane == 0) {
#pragma unroll
        for (int j = 0; j < KNN; ++j) {
            out[wave*KNN+j] = bd[j];
            out[NQ*KNN + wave*KNN + j] = (float)bi[j];
        }
    }
}

extern "C" void kernel_launch(void* const* d_in, const int* in_sizes, int n_in,
                              void* d_out, int out_size, void* d_ws, size_t ws_size,
                              hipStream_t stream) {
    const float* points  = (const float*)d_in[0];
    const float* queries = (const float*)d_in[1];
    float* out = (float*)d_out;

    if (ws_size < (size_t)WS_NEED) {
        knn_fallback<<<(NQ * 64 + 255) / 256, 256, 0, stream>>>(points, queries, out);
        return;
    }

    char* ws = (char*)d_ws;
    float4*         packed = (float4*)(ws + PK_OFF);
    unsigned short* cnt    = (unsigned short*)(ws + CNT_OFF);
    unsigned short* il     = (unsigned short*)(ws + IL_OFF);

    pack_kernel<<<NBUN / 256, 256, 0, stream>>>(points, packed);
    knn_main<<<NBLK, 256, 0, stream>>>(packed, queries, cnt, il);
    knn_final<<<NQ / 4, 256, 0, stream>>>(cnt, il, points, queries, out);
}

// Round 26
// 78.861 us; speedup vs baseline: 6.8664x; 6.8664x over previous
//
#include <hip/hip_runtime.h>
#include <math.h>
#include <limits.h>

#define NPTS    50000
#define NCHUNK  16
#define CHUNK   3328             // float4s per chunk (xy plane 1664 + zs plane 1664)
#define CBUN    1664             // bundles per chunk (2 pts/bundle)
#define NGROUP  13
#define NPAD    (NCHUNK * CHUNK) // 53248 float4s total packed
#define NBUN    (NCHUNK * CBUN)  // 26624 bundles
#define NQ      4000
#define KNN     4
#define QG      8                // queries per wave
#define NWAVE   8000             // (NQ/QG) * NCHUNK
#define NBLK    (NWAVE / 4)      // 2000
#define CAP     12               // per-(query,chunk) pool (u16 index-only)
#define BIGF    3.0e38f

// workspace layout (bytes) — identical to r15/r20/r23 (passing)
#define PK_OFF  0
#define CNT_OFF (NPAD * 16)                          // 851968
#define IL_OFF  (CNT_OFF + NQ * NCHUNK * 4)          // 1107968
#define WS_NEED (IL_OFF + NQ * NCHUNK * CAP * 2)     // 2643968 (< 2887296 proven)

typedef float v2f __attribute__((ext_vector_type(2)));

// lex (dist, idx) insert into sorted ascending 4-list
__device__ __forceinline__ void lex_insert(float (&bd)[KNN], int (&bi)[KNN],
                                           float dist, int idx) {
    if (dist < bd[KNN - 1] || (dist == bd[KNN - 1] && idx < bi[KNN - 1])) {
        bd[KNN - 1] = dist; bi[KNN - 1] = idx;
#pragma unroll
        for (int k = KNN - 1; k > 0; --k) {
            bool sw = (bd[k] < bd[k - 1]) || (bd[k] == bd[k - 1] && bi[k] < bi[k - 1]);
            if (sw) {
                float td = bd[k]; bd[k] = bd[k - 1]; bd[k - 1] = td;
                int   ti = bi[k]; bi[k] = bi[k - 1]; bi[k - 1] = ti;
            }
        }
    }
}

// butterfly merge of per-lane sorted 4-lists -> wave-global lex top-4 (all lanes)
__device__ __forceinline__ void wave_merge4(float (&bd)[KNN], int (&bi)[KNN]) {
    for (int m = 1; m < 64; m <<= 1) {
        float od[KNN]; int oi[KNN];
#pragma unroll
        for (int j = 0; j < KNN; ++j) {
            od[j] = __shfl_xor(bd[j], m, 64);
            oi[j] = __shfl_xor(bi[j], m, 64);
        }
        float md[KNN]; int mi[KNN]; int a = 0, b = 0;
#pragma unroll
        for (int j = 0; j < KNN; ++j) {
            const bool takeA = (bd[a] < od[b]) || (bd[a] == od[b] && bi[a] <= oi[b]);
            if (takeA) { md[j] = bd[a]; mi[j] = bi[a]; ++a; }
            else       { md[j] = od[b]; mi[j] = oi[b]; ++b; }
        }
#pragma unroll
        for (int j = 0; j < KNN; ++j) { bd[j] = md[j]; bi[j] = mi[j]; }
    }
}

// ---------------- pack: chunk-major SoA planes: xy[1664] then zs[1664] ------
__global__ __launch_bounds__(256) void pack_kernel(const float* __restrict__ pts,
                                                   float4* __restrict__ packed) {
    int t = blockIdx.x * 256 + threadIdx.x;   // grid = NBUN/256 = 104
    int p0 = 2 * t, p1 = 2 * t + 1;
    float x0 = 0.f, y0 = 0.f, z0 = 0.f, s0 = BIGF;
    float x1 = 0.f, y1 = 0.f, z1 = 0.f, s1 = BIGF;
    if (p0 < NPTS) {
        x0 = pts[3*p0]; y0 = pts[3*p0+1]; z0 = pts[3*p0+2];
        s0 = __fadd_rn(__fadd_rn(__fmul_rn(x0,x0), __fmul_rn(y0,y0)), __fmul_rn(z0,z0));
    }
    if (p1 < NPTS) {
        x1 = pts[3*p1]; y1 = pts[3*p1+1]; z1 = pts[3*p1+2];
        s1 = __fadd_rn(__fadd_rn(__fmul_rn(x1,x1), __fmul_rn(y1,y1)), __fmul_rn(z1,z1));
    }
    const int c = t / CBUN, i = t - c * CBUN;
    packed[c * CHUNK + i]        = make_float4(x0, x1, y0, y1);   // xy plane
    packed[c * CHUNK + CBUN + i] = make_float4(z0, z1, s0, s1);   // zs plane
}

// packed filter distance for a bundle: d2' = fma chain + s
__device__ __forceinline__ v2f d2pk(float mx, float my, float mz, float qs,
                                    float4 XY, float4 ZS) {
    v2f x = {XY.x, XY.y}, y = {XY.z, XY.w}, z = {ZS.x, ZS.y}, s = {ZS.z, ZS.w};
    v2f t = __builtin_elementwise_fma((v2f){mx, mx}, x, (v2f){qs, qs});
    t = __builtin_elementwise_fma((v2f){my, my}, y, t);
    t = __builtin_elementwise_fma((v2f){mz, mz}, z, t);
    return t + s;
}

// ---------------- main: GLOBAL reads (no staging) + LDS candidate pools -----
__global__ __launch_bounds__(256) void knn_main(const float4* __restrict__ pk4,
                                                const float* __restrict__ queries,
                                                unsigned short* __restrict__ cnt,
                                                unsigned short* __restrict__ il) {
    __shared__ int scnt[32];                  // per-block (query, chunk) pools
    __shared__ unsigned short sil[32][CAP];   // 896 B total -> occupancy VGPR-bound

    const int lane  = threadIdx.x & 63;
    const int widx  = threadIdx.x >> 6;
    const int chunk = blockIdx.x & 15;        // block->chunk: L2 affinity
    const int qg    = (blockIdx.x >> 4) * 4 + widx;   // [0, 500)
    const int qbase = qg * QG;

    if (threadIdx.x < 32) scnt[threadIdx.x] = 0;

    float mx[QG], my[QG], mz[QG], qs[QG];
#pragma unroll
    for (int j = 0; j < QG; ++j) {
        float a = queries[(qbase + j) * 3 + 0];
        float b = queries[(qbase + j) * 3 + 1];
        float c = queries[(qbase + j) * 3 + 2];
        mx[j] = __fmul_rn(-2.f, a);
        my[j] = __fmul_rn(-2.f, b);
        mz[j] = __fmul_rn(-2.f, c);
        qs[j] = __fadd_rn(__fadd_rn(__fmul_rn(a, a), __fmul_rn(b, b)),
                          __fmul_rn(c, c));
    }
    __syncthreads();

    const float4* xy = pk4 + chunk * CHUNK;   // xy plane of this chunk
    const float4* zs = xy + CBUN;             // zs plane

    // ---- pass A: per-lane packed min of d2' per query (global reads) ----
    v2f mn[QG];
#pragma unroll
    for (int j = 0; j < QG; ++j) mn[j] = (v2f){BIGF, BIGF};

#pragma unroll 1
    for (int g = 0; g < NGROUP; ++g) {
        const int bA = g * 128 + lane;
        float4 A1 = xy[bA],      A2 = zs[bA];
        float4 B1 = xy[bA + 64], B2 = zs[bA + 64];
#pragma unroll
        for (int j = 0; j < QG; ++j) {
            v2f ta = d2pk(mx[j], my[j], mz[j], qs[j], A1, A2);
            v2f tb = d2pk(mx[j], my[j], mz[j], qs[j], B1, B2);
            mn[j] = __builtin_elementwise_min(mn[j],
                        __builtin_elementwise_min(ta, tb));
        }
    }

    // ---- tau2: 4th-distinct-smallest of 64 lane mins + abs/rel margin ----
    float tau2[QG];
#pragma unroll
    for (int j = 0; j < QG; ++j) {
        float v = fminf(mn[j].x, mn[j].y), tau = v;
#pragma unroll
        for (int r = 0; r < 4; ++r) {
            float t = v;
#pragma unroll
            for (int s = 1; s < 64; s <<= 1) t = fminf(t, __shfl_xor(t, s, 64));
            tau = t;
            v = (v == t) ? BIGF : v;
        }
        tau2[j] = fmaf(tau, 1.00001f, 1e-4f);   // covers packed-vs-exact + sqrt ties
    }

    // ---- pass B: rescan (global reads), rare pushes into LDS pools ----
#pragma unroll 1
    for (int g = 0; g < NGROUP; ++g) {
        const int bA = g * 128 + lane;
        float4 A1 = xy[bA],      A2 = zs[bA];
        float4 B1 = xy[bA + 64], B2 = zs[bA + 64];
        const int pb = 2 * (chunk * CBUN + bA);        // global point idx of A.x
#pragma unroll
        for (int j = 0; j < QG; ++j) {
            v2f ta = d2pk(mx[j], my[j], mz[j], qs[j], A1, A2);
            v2f tb = d2pk(mx[j], my[j], mz[j], qs[j], B1, B2);
            v2f m2 = __builtin_elementwise_min(ta, tb);
            float m1 = fminf(m2.x, m2.y);
            if (m1 <= tau2[j]) {
                const int lp = widx * QG + j;          // local pool [0,32)
                if (ta.x <= tau2[j]) { int pos = atomicAdd(&scnt[lp], 1); if (pos < CAP) sil[lp][pos] = (unsigned short)pb; }
                if (ta.y <= tau2[j]) { int pos = atomicAdd(&scnt[lp], 1); if (pos < CAP) sil[lp][pos] = (unsigned short)(pb + 1); }
                if (tb.x <= tau2[j]) { int pos = atomicAdd(&scnt[lp], 1); if (pos < CAP) sil[lp][pos] = (unsigned short)(pb + 128); }
                if (tb.y <= tau2[j]) { int pos = atomicAdd(&scnt[lp], 1); if (pos < CAP) sil[lp][pos] = (unsigned short)(pb + 129); }
            }
        }
    }

    // ---- writeback: coalesced dump per block (no global atomics) ----
    __syncthreads();
    const int qb0 = (blockIdx.x >> 4) * 32;            // first query of this block
    if (threadIdx.x < 32)
        cnt[(qb0 + threadIdx.x) * NCHUNK + chunk] = (unsigned short)scnt[threadIdx.x];
    for (int s = threadIdx.x; s < 32 * CAP; s += 256) {   // all 384 slots
        const int t = s / CAP, k = s - t * CAP;
        il[((qb0 + t) * NCHUNK + chunk) * CAP + k] = sil[t][k];
    }
}

// ---------------- final: one wave per query, 192 slots, EXACT arithmetic ----
__global__ __launch_bounds__(256) void knn_final(const unsigned short* __restrict__ cnt,
                                                 const unsigned short* __restrict__ il,
                                                 const float* __restrict__ points,
                                                 const float* __restrict__ queries,
                                                 float* __restrict__ out) {
    const int q    = blockIdx.x * 4 + (threadIdx.x >> 6);  // [0, 4000)
    const int lane = threadIdx.x & 63;

    const float q0 = queries[q*3+0], q1 = queries[q*3+1], q2v = queries[q*3+2];
    const float q2s = __fadd_rn(__fadd_rn(__fmul_rn(q0,q0), __fmul_rn(q1,q1)),
                                __fmul_rn(q2v,q2v));

    float bd[KNN]; int bi[KNN];
#pragma unroll
    for (int k = 0; k < KNN; ++k) { bd[k] = INFINITY; bi[k] = INT_MAX; }

    // per-lane slots lane, lane+64, lane+128 over the 16 pools x CAP=12
    int sc[3], sj[3], sn[3];
    bool o = false;
#pragma unroll
    for (int t = 0; t < 3; ++t) {
        int s = lane + t * 64;
        int c = s / CAP;
        sc[t] = c; sj[t] = s - c * CAP;
        sn[t] = (int)cnt[q * NCHUNK + c];
        o = o || (sn[t] > CAP);
    }

    if (!__any(o)) {
#pragma unroll
        for (int t = 0; t < 3; ++t) {
            if (sj[t] < sn[t]) {
                int idx = (int)il[(q * NCHUNK + sc[t]) * CAP + sj[t]];
                float x = points[idx*3], y = points[idx*3+1], z = points[idx*3+2];
                float p2s = __fadd_rn(__fadd_rn(__fmul_rn(x,x), __fmul_rn(y,y)), __fmul_rn(z,z));
                float dot = __fadd_rn(__fadd_rn(__fmul_rn(q0,x), __fmul_rn(q1,y)), __fmul_rn(q2v,z));
                float d2  = __fsub_rn(__fadd_rn(q2s, p2s), __fmul_rn(2.0f, dot));
                lex_insert(bd, bi, __fsqrt_rn(fmaxf(d2, 0.f)), idx);
            }
        }
    } else {
        // overflow repair (rare): wave-parallel brute force, exact arithmetic
        for (int p = lane; p < NPTS; p += 64) {
            float x = points[p*3], y = points[p*3+1], z = points[p*3+2];
            float p2s = __fadd_rn(__fadd_rn(__fmul_rn(x,x), __fmul_rn(y,y)), __fmul_rn(z,z));
            float dot = __fadd_rn(__fadd_rn(__fmul_rn(q0,x), __fmul_rn(q1,y)), __fmul_rn(q2v,z));
            float d2  = __fsub_rn(__fadd_rn(q2s, p2s), __fmul_rn(2.0f, dot));
            lex_insert(bd, bi, __fsqrt_rn(fmaxf(d2, 0.f)), p);
        }
    }

    wave_merge4(bd, bi);

    if (lane == 0) {
#pragma unroll
        for (int k = 0; k < KNN; ++k) {
            out[q * KNN + k]            = bd[k];
            out[NQ * KNN + q * KNN + k] = (float)bi[k];
        }
    }
}

// ---------------- fallback (round-1 kernel, passed) if ws too small ---------
__global__ __launch_bounds__(256) void knn_fallback(const float* __restrict__ points,
                                                    const float* __restrict__ queries,
                                                    float* __restrict__ out) {
    const int gtid = blockIdx.x * blockDim.x + threadIdx.x;
    const int wave = gtid >> 6;
    const int lane = threadIdx.x & 63;
    if (wave >= NQ) return;
    const float q0 = queries[wave*3+0], q1 = queries[wave*3+1], q2v = queries[wave*3+2];
    const float q2s = __fadd_rn(__fadd_rn(__fmul_rn(q0,q0), __fmul_rn(q1,q1)), __fmul_rn(q2v,q2v));
    float bd[KNN]; int bi[KNN];
#pragma unroll
    for (int j = 0; j < KNN; ++j) { bd[j] = INFINITY; bi[j] = INT_MAX; }
    for (int p = lane; p < NPTS; p += 64) {
        float x = points[p*3], y = points[p*3+1], z = points[p*3+2];
        float p2s = __fadd_rn(__fadd_rn(__fmul_rn(x,x), __fmul_rn(y,y)), __fmul_rn(z,z));
        float dot = __fadd_rn(__fadd_rn(__fmul_rn(q0,x), __fmul_rn(q1,y)), __fmul_rn(q2v,z));
        float d2 = __fsub_rn(__fadd_rn(q2s, p2s), __fmul_rn(2.0f, dot));
        lex_insert(bd, bi, __fsqrt_rn(fmaxf(d2, 0.f)), p);
    }
    wave_merge4(bd, bi);
    if (lane == 0) {
#pragma unroll
        for (int j = 0; j < KNN; ++j) {
            out[wave*KNN+j] = bd[j];
            out[NQ*KNN + wave*KNN + j] = (float)bi[j];
        }
    }
}

extern "C" void kernel_launch(void* const* d_in, const int* in_sizes, int n_in,
                              void* d_out, int out_size, void* d_ws, size_t ws_size,
                              hipStream_t stream) {
    const float* points  = (const float*)d_in[0];
    const float* queries = (const float*)d_in[1];
    float* out = (float*)d_out;

    if (ws_size < (size_t)WS_NEED) {
        knn_fallback<<<(NQ * 64 + 255) / 256, 256, 0, stream>>>(points, queries, out);
        return;
    }

    char* ws = (char*)d_ws;
    float4*         packed = (float4*)(ws + PK_OFF);
    unsigned short* cnt    = (unsigned short*)(ws + CNT_OFF);
    unsigned short* il     = (unsigned short*)(ws + IL_OFF);

    pack_kernel<<<NBUN / 256, 256, 0, stream>>>(points, packed);
    knn_main<<<NBLK, 256, 0, stream>>>(packed, queries, cnt, il);
    knn_final<<<NQ / 4, 256, 0, stream>>>(cnt, il, points, queries, out);
}